// Round 5
// baseline (287.841 us; speedup 1.0000x reference)
//
#include <hip/hip_runtime.h>
#include <hip/hip_bf16.h>
#include <math.h>

// Cylindrical pooling: for each box, select first S in-radius points (ascending
// index), append box velocity, zero remaining slots.
//
// Exact f32 semantics: reference computes dis = sqrt_rn(dx*dx + dy*dy) (no FMA
// contraction) and tests dis <= r. sqrt_rn is monotone, so dis <= r  <=>
// d2 <= T where T = max{x : sqrt_rn(x) <= r} (nextafter walk, exact).
//
// Two-kernel saturation-adaptive plan:
//  K1: per box, count groups 0..ngrpA-1 (first 8192 pts). If the box already
//      has >= S hits there (~93% on gaussian data), scan+emit it right here
//      (counts live in LDS). Else write counts+flag for K2. Also zeroes done[].
//  K2: counts remaining groups for unsaturated boxes only; the last block to
//      finish a box (device-scope done[] counter + threadfences) scans the
//      full prefix and emits that box. Distribution affects speed only.

#define P0GRP 128   // groups in pass A (64 points each)

__device__ __forceinline__ float box_radius(const float* __restrict__ b) {
    float hx = __fmul_rn(b[3], 0.5f);
    float hy = __fmul_rn(b[4], 0.5f);
    float nrm = __fsqrt_rn(__fadd_rn(__fmul_rn(hx, hx), __fmul_rn(hy, hy)));
    return __fmul_rn(nrm, 1.1f);   // GAMMA
}

// largest finite x with __fsqrt_rn(x) <= r  (r >= 0); uniform short walk
__device__ float sqrt_le_threshold(float r) {
    float x = __fmul_rn(r, r);
    #pragma unroll 1
    for (int i = 0; i < 16; ++i) {
        float nx = nextafterf(x, INFINITY);
        if (__fsqrt_rn(nx) <= r) x = nx; else break;
    }
    #pragma unroll 1
    for (int i = 0; i < 16; ++i) {
        if (__fsqrt_rn(x) <= r) break;
        x = nextafterf(x, -INFINITY);
    }
    return x;
}

__device__ __forceinline__ bool pt_in(float bx, float by, float T,
                                      float px, float py) {
    float dx = __fsub_rn(bx, px);
    float dy = __fsub_rn(by, py);
    float d2 = __fadd_rn(__fmul_rn(dx, dx), __fmul_rn(dy, dy));
    return d2 <= T;
}

// ---------------- K1: prefix counts + emit saturated boxes ----------------
// Grid: M blocks x 1024 threads. Box params computed redundantly (uniform).
__global__ __launch_bounds__(1024) void kernelA(
    const float* __restrict__ pts, const float* __restrict__ boxes,
    int* __restrict__ counts, float4* __restrict__ bprep, int* __restrict__ done,
    float* __restrict__ out, int N, int M, int S, int ngrp, int ngrpA) {
    extern __shared__ int s_work[];        // S + 64 entries
    __shared__ int s_cnt[P0GRP];
    __shared__ int s_tot[16];
    __shared__ int s_wtot[2];
    __shared__ int s_nwork;

    int m = blockIdx.x;
    int tid = threadIdx.x;
    int lane = tid & 63;
    int wid = tid >> 6;

    const float* b = boxes + (size_t)m * 9;
    float bx = b[0], by = b[1];
    float T = sqrt_le_threshold(box_radius(b));
    float vx = b[7], vy = b[8];

    if (tid == 0) { done[m] = 0; s_nwork = 0; }

    int tot = 0;
    for (int g = wid; g < ngrpA; g += 16) {
        int p = g * 64 + lane;
        bool v = p < N;
        float px = v ? pts[(size_t)p * 5 + 0] : 3.0e38f;
        float py = v ? pts[(size_t)p * 5 + 1] : 3.0e38f;
        int c = __popcll(__ballot(pt_in(bx, by, T, px, py)));
        if (lane == 0) s_cnt[g] = c;
        tot += c;
    }
    if (lane == 0) s_tot[wid] = tot;
    __syncthreads();

    int total = 0;
    #pragma unroll
    for (int w = 0; w < 16; ++w) total += s_tot[w];

    if (tid == 0) bprep[m] = make_float4(bx, by, T, __int_as_float(total));
    bool unsat = total < S;
    if (unsat) {
        for (int g = tid; g < ngrpA; g += 1024)
            counts[(size_t)m * ngrp + g] = s_cnt[g];
        if (ngrpA != ngrp) return;         // K2 will finish this box
    }

    // ---- scan groups (<=128) + worklist + emit ----
    int c = (tid < ngrpA) ? s_cnt[tid] : 0;
    int incl = c;
    if (wid < 2) {
        #pragma unroll
        for (int d = 1; d < 64; d <<= 1) {
            int u = __shfl_up(incl, d, 64);
            if (lane >= d) incl += u;
        }
        if (lane == 63) s_wtot[wid] = incl;
    }
    __syncthreads();
    if (tid < ngrpA) {
        int base = incl - c + (wid == 1 ? s_wtot[0] : 0);
        if (c > 0 && base < S) {
            int slot = atomicAdd(&s_nwork, 1);
            s_work[slot] = (base << 16) | tid;
        }
    }
    __syncthreads();
    int nwork = s_nwork;

    for (int i = wid; i < nwork; i += 16) {
        int e = s_work[i];
        int g = e & 0xffff;
        int gbase = e >> 16;
        int p = g * 64 + lane;
        bool in = false;
        float px = 0.f, py = 0.f;
        if (p < N) {
            px = pts[(size_t)p * 5 + 0];
            py = pts[(size_t)p * 5 + 1];
            in = pt_in(bx, by, T, px, py);
        }
        unsigned long long bal = __ballot(in);
        int rank = __popcll(bal & ((1ull << lane) - 1ull));
        int pos = gbase + rank;
        if (in && pos < S) {
            float* o = out + ((size_t)m * S + pos) * 7;
            const float* pp = pts + (size_t)p * 5;
            o[0] = px;    o[1] = py;    o[2] = pp[2];
            o[3] = pp[3]; o[4] = pp[4];
            o[5] = vx;    o[6] = vy;
        }
    }

    int cnt = total < S ? total : S;       // tail only when ngrpA==ngrp && unsat
    size_t outbase = (size_t)m * S * 7;
    for (int i = cnt * 7 + tid; i < S * 7; i += 1024) out[outbase + i] = 0.0f;
}

// ---------------- K2: remaining counts + last-block emission ----------------
// Grid: ntile x msplit blocks, 256 threads, mchunk (<=64) boxes per column.
__global__ __launch_bounds__(256) void kernelB(
    const float* __restrict__ pts, const float* __restrict__ boxes,
    const float4* __restrict__ bprep, int* __restrict__ counts,
    int* __restrict__ done, float* __restrict__ out,
    int N, int M, int S, int ngrp, int ngrpA, int ntile, int mchunk) {
    extern __shared__ int s_work[];        // S + 64 entries
    __shared__ float4 s_box[64];
    __shared__ unsigned long long s_mask;
    __shared__ int s_emit[64];
    __shared__ int s_nemit;
    __shared__ int s_ws[4];
    __shared__ int s_nw;

    int tid = threadIdx.x;
    int lane = tid & 63;
    int wid = tid >> 6;

    int tile = blockIdx.x % ntile;
    int mc = blockIdx.x / ntile;
    int m0 = mc * mchunk;
    int nmb = M - m0; if (nmb > mchunk) nmb = mchunk;

    bool act = false;
    if (tid < nmb) {
        float4 bb = bprep[m0 + tid];
        s_box[tid] = bb;
        act = __float_as_int(bb.w) < S;
    }
    unsigned long long bal0 = __ballot(act);   // wave 0 holds the true mask
    if (tid == 0) { s_mask = bal0; s_nemit = 0; }
    __syncthreads();
    unsigned long long amask = s_mask;
    if (amask == 0) return;                    // block-uniform

    // ---- counting ----
    int pbase = ngrpA * 64 + tile * 1024 + wid * 256;
    int g0 = pbase >> 6;
    if (g0 < ngrp) {
        bool vec4 = (g0 + 4 <= ngrp);          // g0 % 4 == 0 (ngrpA=128)
        float px[4], py[4];
        #pragma unroll
        for (int i = 0; i < 4; ++i) {
            int p = pbase + i * 64 + lane;
            bool v = p < N;
            px[i] = v ? pts[(size_t)p * 5 + 0] : 3.0e38f;
            py[i] = v ? pts[(size_t)p * 5 + 1] : 3.0e38f;
        }
        unsigned long long it = amask;
        while (it) {
            int mm = __builtin_ctzll(it);
            it &= it - 1;
            float4 bb = s_box[mm];
            int cnt[4];
            #pragma unroll
            for (int i = 0; i < 4; ++i)
                cnt[i] = __popcll(__ballot(pt_in(bb.x, bb.y, bb.z, px[i], py[i])));
            if (lane == 0) {
                int* dst = counts + (size_t)(m0 + mm) * ngrp + g0;
                if (vec4) {
                    *reinterpret_cast<int4*>(dst) =
                        make_int4(cnt[0], cnt[1], cnt[2], cnt[3]);
                } else {
                    #pragma unroll
                    for (int i = 0; i < 4; ++i)
                        if (g0 + i < ngrp) dst[i] = cnt[i];
                }
            }
        }
    }
    __syncthreads();

    // ---- publish + last-block detection ----
    __threadfence();                           // release our count writes
    if (tid < nmb && ((amask >> tid) & 1ull)) {
        int old = atomicAdd(&done[m0 + tid], 1);
        if (old == ntile - 1) {
            int s = atomicAdd(&s_nemit, 1);
            s_emit[s] = m0 + tid;
        }
    }
    __syncthreads();
    int ne = s_nemit;
    if (ne == 0) return;
    __threadfence();                           // acquire others' count writes

    // ---- emission for boxes whose counting just completed ----
    int gpt = (ngrp + 255) >> 8;               // <= 16 (launcher guard)
    for (int ei = 0; ei < ne; ++ei) {
        int m = s_emit[ei];
        if (tid == 0) s_nw = 0;
        float4 bb = bprep[m];
        float bx = bb.x, by = bb.y, T = bb.z;
        float vx = boxes[(size_t)m * 9 + 7];
        float vy = boxes[(size_t)m * 9 + 8];
        const int* mcounts = counts + (size_t)m * ngrp;

        int g0e = tid * gpt;
        int c[16];
        int tsum = 0;
        if (gpt == 16 && g0e + 16 <= ngrp) {
            #pragma unroll
            for (int j = 0; j < 4; ++j) {
                int4 v4 = *reinterpret_cast<const int4*>(mcounts + g0e + 4 * j);
                c[4 * j + 0] = v4.x; c[4 * j + 1] = v4.y;
                c[4 * j + 2] = v4.z; c[4 * j + 3] = v4.w;
                tsum += v4.x + v4.y + v4.z + v4.w;
            }
        } else {
            #pragma unroll
            for (int i = 0; i < 16; ++i) {
                int g = g0e + i;
                int cv = (i < gpt && g < ngrp) ? mcounts[g] : 0;
                c[i] = cv; tsum += cv;
            }
        }

        int v = tsum;
        #pragma unroll
        for (int d = 1; d < 64; d <<= 1) {
            int u = __shfl_up(v, d, 64);
            if (lane >= d) v += u;
        }
        if (lane == 63) s_ws[wid] = v;
        __syncthreads();
        int woff = 0, total = 0;
        #pragma unroll
        for (int w = 0; w < 4; ++w) {
            int s = s_ws[w];
            total += s;
            if (w < wid) woff += s;
        }
        int base = woff + (v - tsum);

        #pragma unroll
        for (int i = 0; i < 16; ++i) {
            if (i < gpt) {
                int g = g0e + i;
                if (g < ngrp) {
                    int cv = c[i];
                    if (cv > 0 && base < S) {
                        int slot = atomicAdd(&s_nw, 1);
                        s_work[slot] = (base << 16) | g;
                    }
                    base += cv;
                }
            }
        }
        __syncthreads();
        int nwork = s_nw;

        for (int i = wid; i < nwork; i += 4) {
            int e = s_work[i];
            int g = e & 0xffff;
            int gbase = e >> 16;
            int p = g * 64 + lane;
            bool in = false;
            float px = 0.f, py = 0.f;
            if (p < N) {
                px = pts[(size_t)p * 5 + 0];
                py = pts[(size_t)p * 5 + 1];
                in = pt_in(bx, by, T, px, py);
            }
            unsigned long long bal = __ballot(in);
            int rank = __popcll(bal & ((1ull << lane) - 1ull));
            int pos = gbase + rank;
            if (in && pos < S) {
                float* o = out + ((size_t)m * S + pos) * 7;
                const float* pp = pts + (size_t)p * 5;
                o[0] = px;    o[1] = py;    o[2] = pp[2];
                o[3] = pp[3]; o[4] = pp[4];
                o[5] = vx;    o[6] = vy;
            }
        }

        int cnt = total < S ? total : S;
        size_t outbase = (size_t)m * S * 7;
        for (int i = cnt * 7 + tid; i < S * 7; i += 256) out[outbase + i] = 0.0f;
        __syncthreads();                       // s_work/s_nw reuse barrier
    }
}

// ---------------- Fallback: serialized scan (guards failed) ----------------
__global__ __launch_bounds__(256) void simple_kernel(
    const float* __restrict__ pts, const float* __restrict__ boxes,
    float* __restrict__ out, int N, int M, int S) {
    __shared__ int s_wc[4];
    int m = blockIdx.x;
    int tid = threadIdx.x;
    int lane = tid & 63;
    int wid = tid >> 6;

    const float* b = boxes + (size_t)m * 9;
    float bx = b[0], by = b[1];
    float T = sqrt_le_threshold(box_radius(b));
    float vx = b[7], vy = b[8];

    int base = 0;
    for (int start = 0; start < N && base < S; start += 256) {
        int p = start + tid;
        bool in = false;
        if (p < N) {
            float px = pts[(size_t)p * 5 + 0];
            float py = pts[(size_t)p * 5 + 1];
            in = pt_in(bx, by, T, px, py);
        }
        unsigned long long bal = __ballot(in);
        if (lane == 0) s_wc[wid] = __popcll(bal);
        __syncthreads();
        int off = 0;
        for (int w = 0; w < wid; ++w) off += s_wc[w];
        int pos = base + off + __popcll(bal & ((1ull << lane) - 1ull));
        if (in && pos < S) {
            float* o = out + ((size_t)m * S + pos) * 7;
            const float* pp = pts + (size_t)p * 5;
            o[0] = pp[0]; o[1] = pp[1]; o[2] = pp[2];
            o[3] = pp[3]; o[4] = pp[4];
            o[5] = vx;    o[6] = vy;
        }
        base += s_wc[0] + s_wc[1] + s_wc[2] + s_wc[3];
        __syncthreads();
    }

    int cnt = base < S ? base : S;
    size_t outbase = (size_t)m * S * 7;
    for (int i = cnt * 7 + tid; i < S * 7; i += 256) out[outbase + i] = 0.0f;
}

extern "C" void kernel_launch(void* const* d_in, const int* in_sizes, int n_in,
                              void* d_out, int out_size, void* d_ws, size_t ws_size,
                              hipStream_t stream) {
    const float* pts = (const float*)d_in[0];
    const float* boxes = (const float*)d_in[1];
    float* out = (float*)d_out;

    int N = in_sizes[0] / 5;
    int M = in_sizes[1] / 9;
    int S = out_size / (M * 7);
    int ngrp = (N + 63) / 64;
    int ngrpA = ngrp < P0GRP ? ngrp : P0GRP;

    size_t counts_bytes = ((size_t)M * ngrp * sizeof(int) + 15) & ~(size_t)15;
    size_t bprep_bytes = (size_t)M * sizeof(float4);
    size_t need = counts_bytes + bprep_bytes + (size_t)M * sizeof(int);

    if (ws_size >= need && S < 32768 && ngrp <= 4096) {
        int* counts = (int*)d_ws;
        float4* bprep = (float4*)((char*)d_ws + counts_bytes);
        int* done = (int*)((char*)d_ws + counts_bytes + bprep_bytes);
        size_t lds = (size_t)(S + 64) * sizeof(int);

        kernelA<<<M, 1024, lds, stream>>>(pts, boxes, counts, bprep, done, out,
                                          N, M, S, ngrp, ngrpA);

        if (ngrp > ngrpA) {
            int ntile = (ngrp - ngrpA + 15) / 16;   // 16 groups (1024 pts) per tile
            int msplit = 2048 / ntile;
            if (msplit < 1) msplit = 1;
            if (msplit > M) msplit = M;
            int mchunk = (M + msplit - 1) / msplit;
            if (mchunk > 64) mchunk = 64;
            msplit = (M + mchunk - 1) / mchunk;
            kernelB<<<ntile * msplit, 256, lds, stream>>>(
                pts, boxes, bprep, counts, done, out,
                N, M, S, ngrp, ngrpA, ntile, mchunk);
        }
    } else {
        simple_kernel<<<M, 256, 0, stream>>>(pts, boxes, out, N, M, S);
    }
}

// Round 6
// 26.974 us; speedup vs baseline: 10.6711x; 10.6711x over previous
//
#include <hip/hip_runtime.h>
#include <hip/hip_bf16.h>
#include <math.h>

// Cylindrical pooling: for each box, select first S in-radius points (ascending
// index), append box velocity, zero remaining slots.
//
// Exact f32 semantics: reference computes dis = sqrt_rn(dx*dx + dy*dy) (no FMA
// contraction) and tests dis <= r. sqrt_rn is monotone, so dis <= r  <=>
// d2 <= T where T = max{x : sqrt_rn(x) <= r} (nextafter walk, exact).
//
// Three-kernel saturation-adaptive plan (NO device-scope fences — R5 showed
// __threadfence-based single-kernel fusion costs ~300us on gfx950):
//  A: per box, count groups 0..ngrpA-1 (first 8192 pts). If the box already
//     has >= S hits there (~93% on gaussian data), scan+emit it right here
//     (counts live in LDS). Else write counts+flag for B/C.
//  B: counts remaining groups, unsaturated boxes only (fence-free tiling).
//  C: emission for unsaturated boxes only; saturated blocks exit immediately.
// Kernel launch order on the stream provides all visibility guarantees.

#define P0GRP 128   // groups in pass A (64 points each)

__device__ __forceinline__ float box_radius(const float* __restrict__ b) {
    float hx = __fmul_rn(b[3], 0.5f);
    float hy = __fmul_rn(b[4], 0.5f);
    float nrm = __fsqrt_rn(__fadd_rn(__fmul_rn(hx, hx), __fmul_rn(hy, hy)));
    return __fmul_rn(nrm, 1.1f);   // GAMMA
}

// largest finite x with __fsqrt_rn(x) <= r  (r >= 0); uniform short walk
__device__ float sqrt_le_threshold(float r) {
    float x = __fmul_rn(r, r);
    #pragma unroll 1
    for (int i = 0; i < 16; ++i) {
        float nx = nextafterf(x, INFINITY);
        if (__fsqrt_rn(nx) <= r) x = nx; else break;
    }
    #pragma unroll 1
    for (int i = 0; i < 16; ++i) {
        if (__fsqrt_rn(x) <= r) break;
        x = nextafterf(x, -INFINITY);
    }
    return x;
}

__device__ __forceinline__ bool pt_in(float bx, float by, float T,
                                      float px, float py) {
    float dx = __fsub_rn(bx, px);
    float dy = __fsub_rn(by, py);
    float d2 = __fadd_rn(__fmul_rn(dx, dx), __fmul_rn(dy, dy));
    return d2 <= T;
}

// ---------------- K A: prefix counts + emit saturated boxes ----------------
// Grid: M blocks x 1024 threads. Box params computed redundantly (uniform).
__global__ __launch_bounds__(1024) void kernelA(
    const float* __restrict__ pts, const float* __restrict__ boxes,
    int* __restrict__ counts, float4* __restrict__ bprep,
    float* __restrict__ out, int N, int M, int S, int ngrp, int ngrpA) {
    extern __shared__ int s_work[];        // S + 64 entries
    __shared__ int s_cnt[P0GRP];
    __shared__ int s_tot[16];
    __shared__ int s_wtot[2];
    __shared__ int s_nwork;

    int m = blockIdx.x;
    int tid = threadIdx.x;
    int lane = tid & 63;
    int wid = tid >> 6;

    const float* b = boxes + (size_t)m * 9;
    float bx = b[0], by = b[1];
    float T = sqrt_le_threshold(box_radius(b));
    float vx = b[7], vy = b[8];

    if (tid == 0) s_nwork = 0;

    int tot = 0;
    for (int g = wid; g < ngrpA; g += 16) {
        int p = g * 64 + lane;
        bool v = p < N;
        float px = v ? pts[(size_t)p * 5 + 0] : 3.0e38f;
        float py = v ? pts[(size_t)p * 5 + 1] : 3.0e38f;
        int c = __popcll(__ballot(pt_in(bx, by, T, px, py)));
        if (lane == 0) s_cnt[g] = c;
        tot += c;
    }
    if (lane == 0) s_tot[wid] = tot;
    __syncthreads();

    int total = 0;
    #pragma unroll
    for (int w = 0; w < 16; ++w) total += s_tot[w];

    if (tid == 0) bprep[m] = make_float4(bx, by, T, __int_as_float(total));
    bool unsat = total < S;
    if (unsat) {
        for (int g = tid; g < ngrpA; g += 1024)
            counts[(size_t)m * ngrp + g] = s_cnt[g];
        if (ngrpA != ngrp) return;         // B counts the rest, C emits
    }

    // ---- scan groups (<=128) + worklist + emit (block-local, no fences) ----
    int c = (tid < ngrpA) ? s_cnt[tid] : 0;
    int incl = c;
    if (wid < 2) {
        #pragma unroll
        for (int d = 1; d < 64; d <<= 1) {
            int u = __shfl_up(incl, d, 64);
            if (lane >= d) incl += u;
        }
        if (lane == 63) s_wtot[wid] = incl;
    }
    __syncthreads();
    if (tid < ngrpA) {
        int base = incl - c + (wid == 1 ? s_wtot[0] : 0);
        if (c > 0 && base < S) {
            int slot = atomicAdd(&s_nwork, 1);
            s_work[slot] = (base << 16) | tid;
        }
    }
    __syncthreads();
    int nwork = s_nwork;

    for (int i = wid; i < nwork; i += 16) {
        int e = s_work[i];
        int g = e & 0xffff;
        int gbase = e >> 16;
        int p = g * 64 + lane;
        bool in = false;
        float px = 0.f, py = 0.f;
        if (p < N) {
            px = pts[(size_t)p * 5 + 0];
            py = pts[(size_t)p * 5 + 1];
            in = pt_in(bx, by, T, px, py);
        }
        unsigned long long bal = __ballot(in);
        int rank = __popcll(bal & ((1ull << lane) - 1ull));
        int pos = gbase + rank;
        if (in && pos < S) {
            float* o = out + ((size_t)m * S + pos) * 7;
            const float* pp = pts + (size_t)p * 5;
            o[0] = px;    o[1] = py;    o[2] = pp[2];
            o[3] = pp[3]; o[4] = pp[4];
            o[5] = vx;    o[6] = vy;
        }
    }

    int cnt = total < S ? total : S;       // tail only when ngrpA==ngrp && unsat
    size_t outbase = (size_t)m * S * 7;
    for (int i = cnt * 7 + tid; i < S * 7; i += 1024) out[outbase + i] = 0.0f;
}

// ---------------- K B: remaining counts for unsaturated boxes ----------
// Grid: ntile x msplit blocks, 256 threads. Each wave holds 256 points of
// groups [ngrpA..); per <=64-box chunk, only boxes with satA < S are counted.
// Fence-free: visibility to kernel C is by stream ordering.
__global__ __launch_bounds__(256) void kernelB(
    const float* __restrict__ pts, const float4* __restrict__ bprep,
    int* __restrict__ counts, int N, int M, int S, int ngrp, int ngrpA,
    int ntile, int mchunk) {
    __shared__ float4 s_box[64];
    __shared__ unsigned long long s_mask;
    int tid = threadIdx.x;
    int lane = tid & 63;
    int wid = tid >> 6;

    int tile = blockIdx.x % ntile;
    int mc = blockIdx.x / ntile;
    int m0 = mc * mchunk;
    int nmb = M - m0; if (nmb > mchunk) nmb = mchunk;   // mchunk <= 64

    bool act = false;
    if (tid < nmb) {
        float4 bb = bprep[m0 + tid];
        s_box[tid] = bb;
        act = __float_as_int(bb.w) < S;
    }
    unsigned long long bal = __ballot(act);   // wave 0 holds the real mask
    if (tid == 0) s_mask = bal;
    __syncthreads();
    unsigned long long amask = s_mask;
    if (amask == 0) return;                   // block-uniform

    int pbase = ngrpA * 64 + tile * 1024 + wid * 256;
    int g0 = pbase >> 6;
    if (g0 >= ngrp) return;                   // wave-uniform, no syncs below
    bool vec4 = (g0 + 4 <= ngrp);

    float px[4], py[4];
    #pragma unroll
    for (int i = 0; i < 4; ++i) {
        int p = pbase + i * 64 + lane;
        bool v = p < N;
        px[i] = v ? pts[(size_t)p * 5 + 0] : 3.0e38f;
        py[i] = v ? pts[(size_t)p * 5 + 1] : 3.0e38f;
    }

    while (amask) {
        int mm = __builtin_ctzll(amask);
        amask &= amask - 1;
        float4 bb = s_box[mm];
        int cnt[4];
        #pragma unroll
        for (int i = 0; i < 4; ++i)
            cnt[i] = __popcll(__ballot(pt_in(bb.x, bb.y, bb.z, px[i], py[i])));
        if (lane == 0) {
            int* dst = counts + (size_t)(m0 + mm) * ngrp + g0;
            if (vec4) {
                *reinterpret_cast<int4*>(dst) =
                    make_int4(cnt[0], cnt[1], cnt[2], cnt[3]);
            } else {
                #pragma unroll
                for (int i = 0; i < 4; ++i)
                    if (g0 + i < ngrp) dst[i] = cnt[i];
            }
        }
    }
}

// ---------------- K C: emission for unsaturated boxes only ----------------
// Grid: M blocks x 1024 threads. Saturated blocks (emitted by A) exit after
// one uniform load. ~7% of blocks do the full scan + worklist + emit.
__global__ __launch_bounds__(1024) void kernelC(
    const float* __restrict__ pts, const float* __restrict__ boxes,
    const float4* __restrict__ bprep,
    const int* __restrict__ counts, float* __restrict__ out,
    int N, int M, int S, int ngrp) {
    extern __shared__ int s_work[];        // S + 64 entries
    __shared__ int s_wsum[16];
    __shared__ int s_nwork;

    int m = blockIdx.x;
    float4 bb = bprep[m];
    int satA = __float_as_int(bb.w);
    if (satA >= S) return;                 // emitted by kernelA

    int tid = threadIdx.x;
    int lane = tid & 63;
    int wid = tid >> 6;

    if (tid == 0) s_nwork = 0;

    float bx = bb.x, by = bb.y, T = bb.z;
    float vx = boxes[(size_t)m * 9 + 7];
    float vy = boxes[(size_t)m * 9 + 8];

    const int* my_counts = counts + (size_t)m * ngrp;
    int gpt = (ngrp + 1023) >> 10;         // <= 8 (launcher guard)
    int g0 = tid * gpt;

    int c[8];
    int tsum = 0;
    if (gpt == 4 && (g0 & 3) == 0 && g0 + 3 < ngrp) {
        int4 v4 = *reinterpret_cast<const int4*>(my_counts + g0);
        c[0] = v4.x; c[1] = v4.y; c[2] = v4.z; c[3] = v4.w;
        tsum = c[0] + c[1] + c[2] + c[3];
    } else {
        #pragma unroll
        for (int i = 0; i < 8; ++i) {
            int g = g0 + i;
            c[i] = (i < gpt && g < ngrp) ? my_counts[g] : 0;
            tsum += c[i];
        }
    }

    // wave-inclusive scan of tsum
    int v = tsum;
    #pragma unroll
    for (int d = 1; d < 64; d <<= 1) {
        int u = __shfl_up(v, d, 64);
        if (lane >= d) v += u;
    }
    if (lane == 63) s_wsum[wid] = v;
    __syncthreads();

    int woff = 0, total = 0;
    #pragma unroll
    for (int w = 0; w < 16; ++w) {
        int s = s_wsum[w];
        total += s;
        if (w < wid) woff += s;
    }
    int base = woff + (v - tsum);          // exclusive prefix of thread's groups

    for (int i = 0; i < gpt; ++i) {
        int g = g0 + i;
        if (g < ngrp) {
            int cnt = c[i];
            if (cnt > 0 && base < S) {
                int slot = atomicAdd(&s_nwork, 1);
                s_work[slot] = (base << 16) | g;
            }
            base += cnt;
        }
    }
    __syncthreads();
    int nwork = s_nwork;

    for (int i = wid; i < nwork; i += 16) {
        int e = s_work[i];
        int g = e & 0xffff;
        int gbase = e >> 16;
        int p = g * 64 + lane;
        bool in = false;
        float px = 0.f, py = 0.f;
        if (p < N) {
            px = pts[(size_t)p * 5 + 0];
            py = pts[(size_t)p * 5 + 1];
            in = pt_in(bx, by, T, px, py);
        }
        unsigned long long bal = __ballot(in);
        int rank = __popcll(bal & ((1ull << lane) - 1ull));
        int pos = gbase + rank;
        if (in && pos < S) {
            float* o = out + ((size_t)m * S + pos) * 7;
            const float* pp = pts + (size_t)p * 5;
            o[0] = px;    o[1] = py;    o[2] = pp[2];
            o[3] = pp[3]; o[4] = pp[4];
            o[5] = vx;    o[6] = vy;
        }
    }

    // zero-fill tail slots [min(total,S), S)
    int cnt = total < S ? total : S;
    size_t outbase = (size_t)m * S * 7;
    for (int i = cnt * 7 + tid; i < S * 7; i += 1024) out[outbase + i] = 0.0f;
}

// ---------------- Fallback: serialized scan (guards failed) ----------------
__global__ __launch_bounds__(256) void simple_kernel(
    const float* __restrict__ pts, const float* __restrict__ boxes,
    float* __restrict__ out, int N, int M, int S) {
    __shared__ int s_wc[4];
    int m = blockIdx.x;
    int tid = threadIdx.x;
    int lane = tid & 63;
    int wid = tid >> 6;

    const float* b = boxes + (size_t)m * 9;
    float bx = b[0], by = b[1];
    float T = sqrt_le_threshold(box_radius(b));
    float vx = b[7], vy = b[8];

    int base = 0;
    for (int start = 0; start < N && base < S; start += 256) {
        int p = start + tid;
        bool in = false;
        if (p < N) {
            float px = pts[(size_t)p * 5 + 0];
            float py = pts[(size_t)p * 5 + 1];
            in = pt_in(bx, by, T, px, py);
        }
        unsigned long long bal = __ballot(in);
        if (lane == 0) s_wc[wid] = __popcll(bal);
        __syncthreads();
        int off = 0;
        for (int w = 0; w < wid; ++w) off += s_wc[w];
        int pos = base + off + __popcll(bal & ((1ull << lane) - 1ull));
        if (in && pos < S) {
            float* o = out + ((size_t)m * S + pos) * 7;
            const float* pp = pts + (size_t)p * 5;
            o[0] = pp[0]; o[1] = pp[1]; o[2] = pp[2];
            o[3] = pp[3]; o[4] = pp[4];
            o[5] = vx;    o[6] = vy;
        }
        base += s_wc[0] + s_wc[1] + s_wc[2] + s_wc[3];
        __syncthreads();
    }

    int cnt = base < S ? base : S;
    size_t outbase = (size_t)m * S * 7;
    for (int i = cnt * 7 + tid; i < S * 7; i += 256) out[outbase + i] = 0.0f;
}

extern "C" void kernel_launch(void* const* d_in, const int* in_sizes, int n_in,
                              void* d_out, int out_size, void* d_ws, size_t ws_size,
                              hipStream_t stream) {
    const float* pts = (const float*)d_in[0];
    const float* boxes = (const float*)d_in[1];
    float* out = (float*)d_out;

    int N = in_sizes[0] / 5;
    int M = in_sizes[1] / 9;
    int S = out_size / (M * 7);
    int ngrp = (N + 63) / 64;
    int ngrpA = ngrp < P0GRP ? ngrp : P0GRP;

    size_t counts_bytes = ((size_t)M * ngrp * sizeof(int) + 15) & ~(size_t)15;
    size_t need = counts_bytes + (size_t)M * sizeof(float4);

    if (ws_size >= need && S < 32768 && ngrp <= 4096) {
        int* counts = (int*)d_ws;
        float4* bprep = (float4*)((char*)d_ws + counts_bytes);
        size_t lds = (size_t)(S + 64) * sizeof(int);

        kernelA<<<M, 1024, lds, stream>>>(pts, boxes, counts, bprep, out,
                                          N, M, S, ngrp, ngrpA);

        if (ngrp > ngrpA) {
            int ntile = (ngrp - ngrpA + 15) / 16;   // 16 groups (1024 pts)/tile
            int msplit = 2048 / ntile;
            if (msplit < 1) msplit = 1;
            if (msplit > M) msplit = M;
            int mchunk = (M + msplit - 1) / msplit;
            if (mchunk > 64) mchunk = 64;
            msplit = (M + mchunk - 1) / mchunk;
            kernelB<<<ntile * msplit, 256, 0, stream>>>(
                pts, bprep, counts, N, M, S, ngrp, ngrpA, ntile, mchunk);

            kernelC<<<M, 1024, lds, stream>>>(pts, boxes, bprep, counts, out,
                                              N, M, S, ngrp);
        }
    } else {
        simple_kernel<<<M, 256, 0, stream>>>(pts, boxes, out, N, M, S);
    }
}